// Round 5
// baseline (382.768 us; speedup 1.0000x reference)
//
#include <hip/hip_runtime.h>
#include <math.h>

// ---------------------------------------------------------------------------
// GAT IoT classifier — round 26: barrier-free streaming GEMMs.
// r25 post-mortem: 128x128 tile regressed non-agg time (228 -> 247 us); both
// tile shapes leave GEMMs at ~60-100 TF because skinny K (128/256) gives only
// 4-8 K-steps -> every 2-barrier K-step eats a full HBM-latency staging stall
// that never amortizes. r26 restructures: B (<=128 KB, shared) staged in LDS
// ONCE per block ([NK][64][40] bank-safe chunks), single __syncthreads, then
// each wave streams its own 32 A-rows global->VGPR->MFMA with ZERO barriers
// in the K-loop (A-frag load row=lane&15, k=(lane>>4)*8 is one 64B line per
// row -> fully coalesced). A re-read x4 across 64-col panels is L2/L3-served
// sequential traffic. Aggregate: r25 verbatim (66.3 us measured plateau).
// Predicted: GEMMs ~20-30 us each, head ~10; total ~280-310 us.
// ---------------------------------------------------------------------------

typedef __attribute__((ext_vector_type(8))) _Float16 half8v;  // 8 fp16 (4 VGPRs)
typedef __attribute__((ext_vector_type(4))) float f32x4;

__device__ __forceinline__ float lrelu(float x) { return x > 0.f ? x : 0.2f * x; }
__device__ __forceinline__ float elu1(float x) { return x > 0.f ? x : (__expf(x) - 1.f); }

// ---------------- weights -> transposed fp16 + indeg zeroing, one launch ------
__global__ void convert_weights_kernel(const float* __restrict__ W1, const float* __restrict__ W2,
                                       const float* __restrict__ lw1,
                                       _Float16* __restrict__ o1, _Float16* __restrict__ o2,
                                       _Float16* __restrict__ o3, int* __restrict__ indeg,
                                       int N) {
  int t = blockIdx.x * blockDim.x + threadIdx.x;
  if (t < 32768) {                       // W1
    int n = t >> 7, k = t & 127;
    o1[t] = (_Float16)W1[(long)k * 256 + n];
  } else if (t < 98304) {                // W2
    int i = t - 32768;
    int n = i >> 8, k = i & 255;
    o2[i] = (_Float16)W2[(long)k * 256 + n];
  } else if (t < 114688) {               // lw1
    int i = t - 98304;
    int n = i >> 8, k = i & 255;
    o3[i] = (_Float16)lw1[(long)k * 64 + n];
  } else if (t < 114688 + N) {           // indeg zeroing
    indeg[t - 114688] = 0;
  }
}

// ---------------- CSR build ----------------
__global__ void count_kernel(const int* __restrict__ dst, int E, int* __restrict__ indeg) {
  int e = blockIdx.x * blockDim.x + threadIdx.x;
  if (e < E) atomicAdd(&indeg[dst[e]], 1);
}

__global__ void scan_block_kernel(const int* __restrict__ in, int* __restrict__ incl,
                                  int* __restrict__ bsum, int N) {
  __shared__ int wsum[16];
  int gid = blockIdx.x * 1024 + threadIdx.x;
  int lane = threadIdx.x & 63, w = threadIdx.x >> 6;
  int v = (gid < N) ? in[gid] : 0;
  int sv = v;
#pragma unroll
  for (int o = 1; o < 64; o <<= 1) {
    int t = __shfl_up(sv, o);
    if (lane >= o) sv += t;
  }
  if (lane == 63) wsum[w] = sv;
  __syncthreads();
  if (w == 0) {
    int bs = (lane < 16) ? wsum[lane] : 0;
#pragma unroll
    for (int o = 1; o < 16; o <<= 1) {
      int t = __shfl_up(bs, o);
      if (lane >= o) bs += t;
    }
    if (lane < 16) wsum[lane] = bs;
  }
  __syncthreads();
  if (w > 0) sv += wsum[w - 1];
  if (gid < N) incl[gid] = sv;
  if (threadIdx.x == 1023) bsum[blockIdx.x] = sv;
}

__global__ void scan_finalize_kernel(const int* __restrict__ in, const int* __restrict__ incl,
                                     const int* __restrict__ bsum, int* __restrict__ off,
                                     int* __restrict__ cursor, int N) {
  int gid = blockIdx.x * blockDim.x + threadIdx.x;
  if (gid >= N) return;
  int b = gid >> 10;
  int carry = 0;
  for (int k = 0; k < b; ++k) carry += bsum[k];
  int ic = incl[gid] + carry;
  off[gid + 1] = ic;
  cursor[gid] = ic - in[gid];
  if (gid == 0) off[0] = 0;
}

__global__ void fill_kernel(const int* __restrict__ src, const int* __restrict__ dst, int E,
                            int* __restrict__ cursor, int* __restrict__ csr_src) {
  int e = blockIdx.x * blockDim.x + threadIdx.x;
  if (e < E) {
    int pos = atomicAdd(&cursor[dst[e]], 1);
    csr_src[pos] = src[e];
  }
}

// ---------------- streaming fp16 MFMA GEMM + attn epilogue ----------------
// C[M,256] = A[M,K] x W[K,256]; W transposed [256][K]. Grid (4, Mp/128):
// blockIdx.x = 64-col panel (== head). B panel staged in LDS once
// ([NK][64][40] bank-safe chunks), ONE barrier; then each of 4 waves streams
// its 32 A-rows global->VGPR (coalesced frag loads) -> MFMA, no K-loop
// barriers. acc[2][4]: rows wave*32 + mi*16, cols = panel.
template <typename AT, int K>
__launch_bounds__(256)
__global__ void gemm_stream_attn_kernel(const AT* __restrict__ A,
                                        const _Float16* __restrict__ B,
                                        const float* __restrict__ att_s,
                                        const float* __restrict__ att_d,
                                        _Float16* __restrict__ C,
                                        float* __restrict__ a_s, float* __restrict__ a_d,
                                        int M) {
  constexpr int NK = K / 32;
  __shared__ _Float16 Bs[NK][64][40];
  int tid = threadIdx.x;
  int lane = tid & 63, wave = tid >> 6;
  int bm = blockIdx.y * 128;
  int panel = blockIdx.x;
  int cbase = panel * 64;
  {  // stage B panel (64 cols x K) once
    int col = tid >> 2, kc = (tid & 3) * 8;
    const _Float16* Bp = B + (long)(cbase + col) * K + kc;
#pragma unroll
    for (int ks = 0; ks < NK; ++ks)
      *(uint4*)&Bs[ks][col][kc] = *(const uint4*)(Bp + ks * 32);
  }
  __syncthreads();
  int fm = lane & 15, fq = lane >> 4;
  int row0 = bm + wave * 32 + fm;   // A-frag row for mi=0 (row = lane&15)
  int row1 = row0 + 16;             // mi=1
  const AT* Ap0 = A + (long)row0 * K + fq * 8;
  const AT* Ap1 = A + (long)row1 * K + fq * 8;
  bool ok0 = row0 < M, ok1 = row1 < M;
  f32x4 acc[2][4];
#pragma unroll
  for (int mi = 0; mi < 2; ++mi)
#pragma unroll
    for (int ni = 0; ni < 4; ++ni) acc[mi][ni] = (f32x4){0.f, 0.f, 0.f, 0.f};
#pragma unroll
  for (int ks = 0; ks < NK; ++ks) {
    half8v a0 = {0, 0, 0, 0, 0, 0, 0, 0}, a1 = {0, 0, 0, 0, 0, 0, 0, 0};
    if constexpr (sizeof(AT) == 4) {
      if (ok0) {
        float4 f0 = *(const float4*)(Ap0 + ks * 32);
        float4 f1 = *(const float4*)(Ap0 + ks * 32 + 4);
        a0 = (half8v){(_Float16)f0.x, (_Float16)f0.y, (_Float16)f0.z, (_Float16)f0.w,
                      (_Float16)f1.x, (_Float16)f1.y, (_Float16)f1.z, (_Float16)f1.w};
      }
      if (ok1) {
        float4 f0 = *(const float4*)(Ap1 + ks * 32);
        float4 f1 = *(const float4*)(Ap1 + ks * 32 + 4);
        a1 = (half8v){(_Float16)f0.x, (_Float16)f0.y, (_Float16)f0.z, (_Float16)f0.w,
                      (_Float16)f1.x, (_Float16)f1.y, (_Float16)f1.z, (_Float16)f1.w};
      }
    } else {
      if (ok0) a0 = *(const half8v*)(Ap0 + ks * 32);
      if (ok1) a1 = *(const half8v*)(Ap1 + ks * 32);
    }
    half8v bh[4];
#pragma unroll
    for (int ni = 0; ni < 4; ++ni) bh[ni] = *(const half8v*)&Bs[ks][ni * 16 + fm][fq * 8];
#pragma unroll
    for (int ni = 0; ni < 4; ++ni) {
      acc[0][ni] = __builtin_amdgcn_mfma_f32_16x16x32_f16(a0, bh[ni], acc[0][ni], 0, 0, 0);
      acc[1][ni] = __builtin_amdgcn_mfma_f32_16x16x32_f16(a1, bh[ni], acc[1][ni], 0, 0, 0);
    }
  }
  // epilogue: C store + attn dots (panel == head)
  int headi = panel;
  float asv[4], adv[4];
#pragma unroll
  for (int ni = 0; ni < 4; ++ni) {
    int col = cbase + ni * 16 + fm;
    asv[ni] = att_s[col];
    adv[ni] = att_d[col];
  }
#pragma unroll
  for (int mi = 0; mi < 2; ++mi) {
    int rowb = bm + wave * 32 + mi * 16 + fq * 4;
#pragma unroll
    for (int r = 0; r < 4; ++r) {
      int row = rowb + r;
      float sp = 0.f, dp = 0.f;
#pragma unroll
      for (int ni = 0; ni < 4; ++ni) {
        float v = acc[mi][ni][r];
        sp = fmaf(v, asv[ni], sp);
        dp = fmaf(v, adv[ni], dp);
        if (row < M) C[(long)row * 256 + cbase + ni * 16 + fm] = (_Float16)v;
      }
#pragma unroll
      for (int o = 1; o < 16; o <<= 1) {
        sp += __shfl_xor(sp, o);
        dp += __shfl_xor(dp, o);
      }
      if (fm == 0 && row < M) {
        a_s[(long)row * 4 + headi] = sp;
        a_d[(long)row * 4 + headi] = dp;
      }
    }
  }
}

// ---------------- streaming fp16 MFMA head (cols=64, K=256) ----------------
__launch_bounds__(256)
__global__ void head_stream_kernel(const _Float16* __restrict__ A, const _Float16* __restrict__ B,
                                   const float* __restrict__ lb1, const float* __restrict__ lw2,
                                   const float* __restrict__ lb2, float* __restrict__ out, int M) {
  constexpr int NK = 8;  // K=256
  __shared__ _Float16 Bs[NK][64][40];
  int tid = threadIdx.x;
  int lane = tid & 63, wave = tid >> 6;
  int bm = blockIdx.x * 128;
  {  // stage B (64 cols x 256) once
    int col = tid >> 2, kc = (tid & 3) * 8;
    const _Float16* Bp = B + (long)col * 256 + kc;
#pragma unroll
    for (int ks = 0; ks < NK; ++ks)
      *(uint4*)&Bs[ks][col][kc] = *(const uint4*)(Bp + ks * 32);
  }
  __syncthreads();
  int fm = lane & 15, fq = lane >> 4;
  int row0 = bm + wave * 32 + fm;
  int row1 = row0 + 16;
  const _Float16* Ap0 = A + (long)row0 * 256 + fq * 8;
  const _Float16* Ap1 = A + (long)row1 * 256 + fq * 8;
  bool ok0 = row0 < M, ok1 = row1 < M;
  f32x4 acc[2][4];
#pragma unroll
  for (int mi = 0; mi < 2; ++mi)
#pragma unroll
    for (int ni = 0; ni < 4; ++ni) acc[mi][ni] = (f32x4){0.f, 0.f, 0.f, 0.f};
#pragma unroll
  for (int ks = 0; ks < NK; ++ks) {
    half8v a0 = {0, 0, 0, 0, 0, 0, 0, 0}, a1 = {0, 0, 0, 0, 0, 0, 0, 0};
    if (ok0) a0 = *(const half8v*)(Ap0 + ks * 32);
    if (ok1) a1 = *(const half8v*)(Ap1 + ks * 32);
    half8v bh[4];
#pragma unroll
    for (int ni = 0; ni < 4; ++ni) bh[ni] = *(const half8v*)&Bs[ks][ni * 16 + fm][fq * 8];
#pragma unroll
    for (int ni = 0; ni < 4; ++ni) {
      acc[0][ni] = __builtin_amdgcn_mfma_f32_16x16x32_f16(a0, bh[ni], acc[0][ni], 0, 0, 0);
      acc[1][ni] = __builtin_amdgcn_mfma_f32_16x16x32_f16(a1, bh[ni], acc[1][ni], 0, 0, 0);
    }
  }
  float lb1c[4], w20[4], w21[4];
#pragma unroll
  for (int ni = 0; ni < 4; ++ni) {
    int col = ni * 16 + fm;
    lb1c[ni] = lb1[col];
    w20[ni] = lw2[col * 2 + 0];
    w21[ni] = lw2[col * 2 + 1];
  }
  float b20 = lb2[0], b21 = lb2[1];
#pragma unroll
  for (int mi = 0; mi < 2; ++mi) {
#pragma unroll
    for (int r = 0; r < 4; ++r) {
      float v0 = 0.f, v1 = 0.f;
#pragma unroll
      for (int ni = 0; ni < 4; ++ni) {
        float s = fmaxf(acc[mi][ni][r] + lb1c[ni], 0.f);
        v0 = fmaf(s, w20[ni], v0);
        v1 = fmaf(s, w21[ni], v1);
      }
#pragma unroll
      for (int o = 1; o < 16; o <<= 1) {
        v0 += __shfl_xor(v0, o);
        v1 += __shfl_xor(v1, o);
      }
      if (fm == 0) {
        int row = bm + wave * 32 + mi * 16 + fq * 4 + r;
        if (row < M) {
          v0 += b20;
          v1 += b21;
          float mx = fmaxf(v0, v1);
          float ls = mx + logf(expf(v0 - mx) + expf(v1 - mx));
          out[(long)row * 2 + 0] = v0 - ls;
          out[(long)row * 2 + 1] = v1 - ls;
        }
      }
    }
  }
}

// ---------------- per-node aggregation: r19 shape, no-max exp --------------
// One wave per node. lane: c = lane&31 (8-col group), hlf = lane>>5 (2 edges
// in flight), head4 = c>>3; logit lanes: h1 = lane&3, sl1 = lane>>2.
// alpha = exp(lrelu(l)) directly (max cancels in e/z; fp32-safe, verified
// r24/r25). 24 VGPR -> 68% occupancy, 3.6 TB/s pattern plateau.
__launch_bounds__(256)
__global__ void gat_aggregate_exp_kernel(const _Float16* __restrict__ h,
                                         const float* __restrict__ a_s,
                                         const float* __restrict__ a_d,
                                         const int* __restrict__ off,
                                         const int* __restrict__ csr_src,
                                         const float* __restrict__ bias,
                                         _Float16* __restrict__ outp, int N) {
  int wid = (blockIdx.x * blockDim.x + threadIdx.x) >> 6;
  int lane = threadIdx.x & 63;
  if (wid >= N) return;
  int c = lane & 31, hlf = lane >> 5, head4 = c >> 3;
  int h1 = lane & 3, sl1 = lane >> 2;
  int beg = off[wid], cnt = off[wid + 1] - beg;
  float ad_h1 = a_d[wid * 4 + h1];
  float psl = __expf(lrelu(a_s[wid * 4 + h1] + ad_h1));
  float pself = __shfl(psl, head4);
  float z = 0.f;
  float acc[8] = {};
  if (hlf == 0) {
    z = pself;
    half8v sr = *(const half8v*)(h + (long)wid * 256 + c * 8);
#pragma unroll
    for (int i = 0; i < 8; ++i) acc[i] = pself * (float)sr[i];
  }
  for (int c0 = 0; c0 < cnt; c0 += 16) {
    int i2 = c0 + (lane & 15);
    int sv = (i2 < cnt) ? csr_src[beg + i2] : 0;
    int i1 = c0 + sl1;
    int spi = __shfl(sv, sl1);
    float pv = (i1 < cnt) ? __expf(lrelu(a_s[(long)spi * 4 + h1] + ad_h1)) : 0.f;
#pragma unroll 4
    for (int j = 0; j < 16; j += 2) {
      if (c0 + j >= cnt) break;
      int e = j + hlf;
      int s = __shfl(sv, e);
      float p = __shfl(pv, e * 4 + head4);
      z += p;
      half8v rv = *(const half8v*)(h + (long)s * 256 + c * 8);
      acc[0] = fmaf(p, (float)rv[0], acc[0]);
      acc[1] = fmaf(p, (float)rv[1], acc[1]);
      acc[2] = fmaf(p, (float)rv[2], acc[2]);
      acc[3] = fmaf(p, (float)rv[3], acc[3]);
      acc[4] = fmaf(p, (float)rv[4], acc[4]);
      acc[5] = fmaf(p, (float)rv[5], acc[5]);
      acc[6] = fmaf(p, (float)rv[6], acc[6]);
      acc[7] = fmaf(p, (float)rv[7], acc[7]);
    }
  }
  z += __shfl_xor(z, 32);
#pragma unroll
  for (int i = 0; i < 8; ++i) acc[i] += __shfl_xor(acc[i], 32);
  if (hlf == 0) {
    float inv = 1.f / z;  // z >= pself > 0
    half8v o;
#pragma unroll
    for (int i = 0; i < 8; ++i) o[i] = (_Float16)elu1(fmaf(acc[i], inv, bias[c * 8 + i]));
    *(half8v*)(outp + (long)wid * 256 + c * 8) = o;
  }
}

// ---------------------------------------------------------------------------
static inline int cdiv(int a, int b) { return (a + b - 1) / b; }

extern "C" void kernel_launch(void* const* d_in, const int* in_sizes, int n_in,
                              void* d_out, int out_size, void* d_ws, size_t ws_size,
                              hipStream_t stream) {
  const float* x = (const float*)d_in[0];
  const int* ei = (const int*)d_in[1];
  const float* W1 = (const float*)d_in[2];
  const float* as1 = (const float*)d_in[3];
  const float* ad1 = (const float*)d_in[4];
  const float* b1 = (const float*)d_in[5];
  const float* W2 = (const float*)d_in[6];
  const float* as2 = (const float*)d_in[7];
  const float* ad2 = (const float*)d_in[8];
  const float* b2 = (const float*)d_in[9];
  const float* lw1 = (const float*)d_in[10];
  const float* lb1 = (const float*)d_in[11];
  const float* lw2 = (const float*)d_in[12];
  const float* lb2 = (const float*)d_in[13];
  float* out = (float*)d_out;

  int N = in_sizes[0] / 128;  // 50000
  int E = in_sizes[1] / 2;    // 800000
  int Mp = cdiv(N, 128) * 128;  // 50048

  char* ws = (char*)d_ws;
  _Float16* Wt1 = (_Float16*)ws; ws += 256 * 128 * 2;
  _Float16* Wt2 = (_Float16*)ws; ws += 256 * 256 * 2;
  _Float16* WL = (_Float16*)ws; ws += 64 * 256 * 2;
  _Float16* C = (_Float16*)ws; ws += (size_t)Mp * 256 * 2;   // GEMM out
  _Float16* h2 = (_Float16*)ws; ws += (size_t)Mp * 256 * 2;  // aggregate out
  float* aS = (float*)ws; ws += (size_t)N * 4 * 4;
  float* aD = (float*)ws; ws += (size_t)N * 4 * 4;
  int* csr_src = (int*)ws; ws += (size_t)E * 4;
  int* indeg = (int*)ws; ws += (size_t)N * 4;
  int* cursor = (int*)ws; ws += (size_t)N * 4;
  int* off = (int*)ws; ws += (size_t)(N + 4) * 4;
  int* incl = (int*)ws; ws += (size_t)N * 4;
  int* bsum = (int*)ws; ws += 64 * 4;

  const int* e_src = ei;
  const int* e_dst = ei + E;
  int nb = cdiv(N, 1024);

  // weight conversion + indeg zeroing (one launch)
  convert_weights_kernel<<<cdiv(114688 + N, 256), 256, 0, stream>>>(W1, W2, lw1, Wt1, Wt2, WL,
                                                                    indeg, N);

  // CSR build
  count_kernel<<<cdiv(E, 256), 256, 0, stream>>>(e_dst, E, indeg);
  scan_block_kernel<<<nb, 1024, 0, stream>>>(indeg, incl, bsum, N);
  scan_finalize_kernel<<<cdiv(N, 256), 256, 0, stream>>>(indeg, incl, bsum, off, cursor, N);
  fill_kernel<<<cdiv(E, 256), 256, 0, stream>>>(e_src, e_dst, E, cursor, csr_src);

  // Layer 1 (K=128, fp32 A streamed+converted in registers)
  gemm_stream_attn_kernel<float, 128><<<dim3(4, Mp / 128), 256, 0, stream>>>(x, Wt1, as1, ad1, C,
                                                                             aS, aD, N);
  gat_aggregate_exp_kernel<<<cdiv(N, 4), 256, 0, stream>>>(C, aS, aD, off, csr_src, b1, h2, N);

  // Layer 2 (K=256, fp16 A)
  gemm_stream_attn_kernel<_Float16, 256><<<dim3(4, Mp / 128), 256, 0, stream>>>(h2, Wt2, as2, ad2,
                                                                                C, aS, aD, N);
  gat_aggregate_exp_kernel<<<cdiv(N, 4), 256, 0, stream>>>(C, aS, aD, off, csr_src, b2, h2, N);

  // Head (streaming, fused epilogue)
  head_stream_kernel<<<Mp / 128, 256, 0, stream>>>(h2, WL, lb1, lw2, lb2, out, N);
}